// Round 1
// baseline (85.717 us; speedup 1.0000x reference)
//
#include <hip/hip_runtime.h>

// Problem constants (fixed by setup_inputs): B=8, N=128, C=64, S=64, basis=20
constexpr int B = 8, N = 128, C = 64, S = 64;
constexpr float INV_AVG = 1.0f / 49.0f;   // AVG_NOBJ
constexpr float SLOPE = 0.01f;            // leaky_relu neg slope

// Workspace layout (float offsets)
constexpr int WS_A = 0;                 // [B][N][S]  diag-x term   (65536)
constexpr int WS_R = 65536;             // [B][N][S]  row (x_j) term
constexpr int WS_C = 131072;            // [B][N][S]  col (x_i) term
constexpr int WS_D = 196608;            // [B][S]     diag agg term (512)
constexpr int WS_E = 197120;            // [B][S]     everywhere agg term

// ---------------------------------------------------------------------------
// Kernel 1: per-batch precompute.
//   Blocks [0,256):  GEMM blocks. Each handles n = blk/32, 4 rows of i.
//                    Builds W1/W2/W3 (aggregation-summed coef matrices) in LDS,
//                    computes A/R/Cc rows.
//   Blocks [256,264): agg blocks, one per n: sum/max/min over i, then D,E.
// ---------------------------------------------------------------------------
__global__ __launch_bounds__(256) void prep_kernel(
    const float* __restrict__ x,      // [B][N][C]
    const float* __restrict__ nobj,   // [B]
    const float* __restrict__ coefs,  // [C][S][20]
    float* __restrict__ ws)
{
  __shared__ float smem[12800];  // 51.2 KB, aliased per branch
  const int tid = threadIdx.x;

  if (blockIdx.x < 256) {
    // ---- GEMM branch ----
    float* W1 = smem;           // [64][64] d-major
    float* W2 = smem + 4096;
    float* W3 = smem + 8192;
    float* xs = smem + 12288;   // 4 rows x 64
    const int n  = blockIdx.x >> 5;
    const int i0 = (blockIdx.x & 31) << 2;

    // Build aggregation-summed weight matrices (op1/op2/op3 coefs are
    // identical across the 4 aggregations -> sum b = 5a+k over a=0..3).
    for (int k = 0; k < 16; ++k) {
      int e = tid + k * 256;            // e = d*64+s
      int d = e >> 6, s = e & 63;
      const float* cp = coefs + d * (S * 20) + s * 20;
      W1[e] = cp[0] + cp[5] + cp[10] + cp[15];
      W2[e] = cp[1] + cp[6] + cp[11] + cp[16];
      W3[e] = cp[2] + cp[7] + cp[12] + cp[17];
    }
    // 4 x-rows, coalesced
    xs[tid] = x[(n * N + i0 + (tid >> 6)) * C + (tid & 63)];
    __syncthreads();

    const int s  = tid & 63;
    const int ii = tid >> 6;
    const float* xr = xs + ii * 64;
    float a1 = 0.f, a2 = 0.f, a3 = 0.f;
#pragma unroll 8
    for (int d = 0; d < 64; ++d) {
      float xv = xr[d];                  // wave-uniform broadcast
      a1 += xv * W1[d * 64 + s];         // stride-1 across lanes: 2-way (free)
      a2 += xv * W2[d * 64 + s];
      a3 += xv * W3[d * 64 + s];
    }
    const int o = (n * N + i0 + ii) * S + s;
    ws[WS_A + o] = a1;
    ws[WS_R + o] = a2;
    ws[WS_C + o] = a3;
  } else {
    // ---- aggregation branch ----
    const int n = blockIdx.x - 256;
    float* xs  = smem;          // [N][C] 8192
    float* ps  = smem + 8192;   // [4][64] partial sums
    float* pmx = smem + 8448;   // [4][64] partial max
    float* pmn = smem + 8704;   // [4][64] partial min
    float* ag  = smem + 8960;   // [4][64] {sum/49, sum/nobj, max, min}

    const float4* xg = (const float4*)(x + n * N * C);
    float4* xs4 = (float4*)xs;
#pragma unroll
    for (int k = 0; k < 8; ++k) xs4[tid + k * 256] = xg[tid + k * 256];
    __syncthreads();

    const int d = tid & 63, grp = tid >> 6;
    float sm = 0.f, mx = -INFINITY, mn = INFINITY;
    for (int i = grp * 32; i < grp * 32 + 32; ++i) {
      float v = xs[i * 64 + d];          // lanes d=0..63 -> 2-way bank (free)
      sm += v;
      mx = fmaxf(mx, v);
      mn = fminf(mn, v);
    }
    ps [grp * 64 + d] = sm;
    pmx[grp * 64 + d] = mx;
    pmn[grp * 64 + d] = mn;
    __syncthreads();

    if (tid < 64) {
      float s0 = ps[tid] + ps[64 + tid] + ps[128 + tid] + ps[192 + tid];
      float m0 = fmaxf(fmaxf(pmx[tid], pmx[64 + tid]),
                       fmaxf(pmx[128 + tid], pmx[192 + tid]));
      float n0 = fminf(fminf(pmn[tid], pmn[64 + tid]),
                       fminf(pmn[128 + tid], pmn[192 + tid]));
      ag[tid]       = s0 * INV_AVG;      // 'sum' aggregation
      ag[64 + tid]  = s0 / nobj[n];      // 'mean'
      ag[128 + tid] = m0;                // 'max'
      ag[192 + tid] = n0;                // 'min'
    }
    __syncthreads();

    if (tid < 64) {
      const int s = tid;
      float dv = 0.f, ev = 0.f;
      for (int d2 = 0; d2 < 64; ++d2) {
        const float* cp = coefs + d2 * (S * 20) + s * 20;
        float a0 = ag[d2], a1 = ag[64 + d2], a2 = ag[128 + d2], a3 = ag[192 + d2];
        dv += a0 * cp[3] + a1 * cp[8] + a2 * cp[13] + a3 * cp[18];
        ev += a0 * cp[4] + a1 * cp[9] + a2 * cp[14] + a3 * cp[19];
      }
      ws[WS_D + n * S + s] = dv;
      ws[WS_E + n * S + s] = ev;
    }
  }
}

// ---------------------------------------------------------------------------
// Kernel 2: assembly. One float4 (4 s-values) per thread; 16 consecutive
// lanes cover one (n,i,j)'s full S=64 row -> 1 KB contiguous per wave.
//   out[n,i,j,s] = leaky(Cc[n,i,s] + R[n,j,s] + E[n,s] + bias[s]
//                        + (i==j) * (A[n,i,s] + D[n,s])) * mask[n,i,j]
// ---------------------------------------------------------------------------
__global__ __launch_bounds__(256) void assemble_kernel(
    const float* __restrict__ ws,
    const float* __restrict__ mask,   // [B][N][N][1]
    const float* __restrict__ bias,   // [S]
    float* __restrict__ out)          // [B][N][N][S]
{
  const float4* A4 = (const float4*)(ws + WS_A);
  const float4* R4 = (const float4*)(ws + WS_R);
  const float4* C4 = (const float4*)(ws + WS_C);
  const float4* D4 = (const float4*)(ws + WS_D);
  const float4* E4 = (const float4*)(ws + WS_E);

  const int g = blockIdx.x * 256 + threadIdx.x;
  const int l = g & 15;          // which float4 of the S row
  const int p = g >> 4;          // (n,i,j) index
  const int j = p & 127;
  const int i = (p >> 7) & 127;
  const int n = p >> 14;

  float4 cc = C4[(n * N + i) * 16 + l];
  float4 rr = R4[(n * N + j) * 16 + l];
  float4 ee = E4[n * 16 + l];
  float4 bb = ((const float4*)bias)[l];
  float  m  = mask[p];

  float v0 = cc.x + rr.x + ee.x + bb.x;
  float v1 = cc.y + rr.y + ee.y + bb.y;
  float v2 = cc.z + rr.z + ee.z + bb.z;
  float v3 = cc.w + rr.w + ee.w + bb.w;

  if (i == j) {
    float4 aa = A4[(n * N + i) * 16 + l];
    float4 dd = D4[n * 16 + l];
    v0 += aa.x + dd.x;
    v1 += aa.y + dd.y;
    v2 += aa.z + dd.z;
    v3 += aa.w + dd.w;
  }

  v0 = (v0 >= 0.f) ? v0 : SLOPE * v0;
  v1 = (v1 >= 0.f) ? v1 : SLOPE * v1;
  v2 = (v2 >= 0.f) ? v2 : SLOPE * v2;
  v3 = (v3 >= 0.f) ? v3 : SLOPE * v3;

  float4 o;
  o.x = v0 * m; o.y = v1 * m; o.z = v2 * m; o.w = v3 * m;
  ((float4*)out)[g] = o;
}

extern "C" void kernel_launch(void* const* d_in, const int* in_sizes, int n_in,
                              void* d_out, int out_size, void* d_ws, size_t ws_size,
                              hipStream_t stream) {
  const float* x     = (const float*)d_in[0];   // [8][128][64]
  const float* mask  = (const float*)d_in[1];   // [8][128][128][1]
  const float* nobj  = (const float*)d_in[2];   // [8]
  const float* coefs = (const float*)d_in[3];   // [64][64][20]
  const float* bias  = (const float*)d_in[4];   // [64]
  float* out = (float*)d_out;                   // [8][128][128][64]
  float* ws  = (float*)d_ws;                    // needs 197632 floats (~790 KB)

  prep_kernel<<<264, 256, 0, stream>>>(x, nobj, coefs, ws);
  // 8*128*128*64 / 4 = 2,097,152 float4 -> 8192 blocks * 256 threads
  assemble_kernel<<<8192, 256, 0, stream>>>(ws, mask, bias, out);
}